// Round 1
// 160.596 us; speedup vs baseline: 1.0171x; 1.0171x over previous
//
#include <hip/hip_runtime.h>
#include <hip/hip_bf16.h>
#include <hip/hip_fp16.h>
#include <math.h>

typedef _Float16 f16x8 __attribute__((ext_vector_type(8)));
typedef _Float16 h2 __attribute__((ext_vector_type(2)));
typedef __fp16 h2amd __attribute__((ext_vector_type(2)));   // builtin return type
typedef float f32x16 __attribute__((ext_vector_type(16)));
typedef float f32x2 __attribute__((ext_vector_type(2)));

#define DH 100      // hidden dim
#define G  4096     // table size per net
#define WSTR 120    // LDS row stride in f16 elems
#define SPB_E 64    // eval: samples per block (4 threads/sample)

// ws float offsets
#define WS_CCW   0      // [0,128)
#define WS_XSC   128    // [128,256)
#define WS_OH0   256    // 3
#define WS_EOH1  260    // 3
#define WS_P01   264    // 64 min/max pairs (logits)  [264,392)
#define WS_RNG   400    // 3 nets x {u0, dlt, inv, pad}  [400,412)
#define WS_TAB   17408  // 3*G table floats

__device__ __forceinline__ unsigned short f2bf(float f) {
    unsigned int u = __float_as_uint(f);
    unsigned int r = (u + 0x7FFFu + ((u >> 16) & 1u)) >> 16;  // RNE
    return (unsigned short)r;
}
__device__ __forceinline__ unsigned int hpk(float a, float b) {
    union { h2amd h; unsigned int u; } c;
    c.h = __builtin_amdgcn_cvt_pkrtz(a, b);
    return c.u;
}
__device__ __forceinline__ h2 hpk2(float a, float b) {
    union { h2amd ha; h2 h; } c;
    c.ha = __builtin_amdgcn_cvt_pkrtz(a, b);
    return c.h;
}

// prep: quadrature consts (block 3), h-MLP consts (blocks 0-2, one net each,
// LDS-staged weights), logits passthrough + per-block min/max partials (all).
__global__ __launch_bounds__(256)
void prep_kernel(const float* __restrict__ logits,
                 const float* __restrict__ hb0,
                 const float* __restrict__ hW1, const float* __restrict__ hb1,
                 const float* __restrict__ hW2, const float* __restrict__ hb2,
                 const float* __restrict__ hW3, const float* __restrict__ hb3,
                 float* __restrict__ ws, float* __restrict__ out2, int n)
{
    __shared__ float hw_s[DH * 101];
    __shared__ float bufA[128], bufB[128];
    __shared__ float rmin_s[4], rmax_s[4];
    const int t = threadIdx.x;
    const int b = blockIdx.x;

    float lmin = 1e30f, lmax = -1e30f;
    for (int i = b * 256 + t; i < n; i += gridDim.x * 256) {
        float v = logits[i];
        out2[i] = v;
        lmin = fminf(lmin, v);
        lmax = fmaxf(lmax, v);
    }
    #pragma unroll
    for (int off = 1; off < 64; off <<= 1) {
        lmin = fminf(lmin, __shfl_xor(lmin, off, 64));
        lmax = fmaxf(lmax, __shfl_xor(lmax, off, 64));
    }
    if ((t & 63) == 0) { rmin_s[t >> 6] = lmin; rmax_s[t >> 6] = lmax; }
    __syncthreads();
    if (t == 0) {
        float m = fminf(fminf(rmin_s[0], rmin_s[1]), fminf(rmin_s[2], rmin_s[3]));
        float M = fmaxf(fmaxf(rmax_s[0], rmax_s[1]), fmaxf(rmax_s[2], rmax_s[3]));
        ws[WS_P01 + 2 * b] = m;
        ws[WS_P01 + 2 * b + 1] = M;
    }

    if (b == 3) {
        if (t < 128) {
            double ccw = 0.0, xs = 0.0;
            if (t <= 100) {
                double s = (double)t;
                for (int j = 0; j <= 100; j += 2) {
                    double wj = (j == 0) ? 1.0 : 2.0 / (1.0 - (double)j * (double)j);
                    double lam;
                    if (t == 0) lam = 0.5;
                    else {
                        lam = cos((double)j * s * M_PI / 100.0);
                        if (t == 100) lam *= 0.5;
                    }
                    ccw += lam * 0.02 * wj;
                }
                xs = (cos(s * M_PI / 100.0) + 1.0) * 0.5;
            }
            ws[WS_CCW + t] = (float)ccw;
            ws[WS_XSC + t] = (float)xs;
        }
    } else if (b < 3) {
        const int k = b;                       // one net per block
        if (t < 128) bufA[t] = (t < DH) ? fmaxf(hb0[k * DH + t], 0.f) : 0.f;
        __syncthreads();
        for (int i = t; i < DH * DH; i += 256) {
            int r = i / DH, c = i - r * DH;
            hw_s[r * 101 + c] = hW1[k * DH * DH + i];
        }
        __syncthreads();
        if (t < DH) {
            float acc = hb1[k * DH + t];
            for (int i = 0; i < DH; ++i) acc = fmaf(hw_s[t * 101 + i], bufA[i], acc);
            bufB[t] = fmaxf(acc, 0.f);
        }
        __syncthreads();
        for (int i = t; i < DH * DH; i += 256) {
            int r = i / DH, c = i - r * DH;
            hw_s[r * 101 + c] = hW2[k * DH * DH + i];
        }
        __syncthreads();
        if (t < DH) {
            float acc = hb2[k * DH + t];
            for (int i = 0; i < DH; ++i) acc = fmaf(hw_s[t * 101 + i], bufB[i], acc);
            bufA[t] = fmaxf(acc, 0.f);
        }
        __syncthreads();
        if (t < 2) {
            float acc = hb3[k * 2 + t];
            const float* w = hW3 + (size_t)(k * 2 + t) * DH;
            for (int i = 0; i < DH; ++i) acc = fmaf(w[i], bufA[i], acc);
            if (t == 0) ws[WS_OH0 + k] = acc;
            else        ws[WS_EOH1 + k] = expf(acc);
        }
    }
}

// probe: single block. Reduces logits min/max partials -> range consts for
// nets 0,1. Then evaluates g_0 at the 202 points {xmin,xmax} x xsc[p] using
// the verified MFMA dataflow, quadratures them into x2(xmin)/x2(xmax), and
// writes the (margin-expanded) range consts for net 2. Exploits monotonicity
// of the mono-net: x2 range = [mono0(xmin), mono0(xmax)].
__global__ __launch_bounds__(256)
void probe_kernel(const float* __restrict__ iW0, const float* __restrict__ ib0,
                  const float* __restrict__ iW1, const float* __restrict__ ib1,
                  const float* __restrict__ iW2, const float* __restrict__ ib2,
                  const float* __restrict__ iW3, const float* __restrict__ ib3,
                  float* __restrict__ ws, int np)
{
    __shared__ __align__(16) _Float16 W1s[DH * WSTR];
    __shared__ __align__(16) _Float16 W2s[DH * WSTR];
    __shared__ unsigned int w0p_s[64], b0p_s[64], w3p_s[64];
    __shared__ float xm_s, xM_s;
    __shared__ float g_s[256];

    const int tid = threadIdx.x;
    const int lane = tid & 63;
    const int wv = tid >> 6;
    const int hf = lane >> 5;
    const bool hfb = (hf != 0);
    const int l31 = lane & 31;
    const int k = 0;

    const float* W1g = iW1 + (size_t)k * DH * DH;
    const float* W2g = iW2 + (size_t)k * DH * DH;

    if (tid < 64) {
        float pm = 1e30f, pM = -1e30f;
        for (int i = tid; i < np; i += 64) {
            pm = fminf(pm, ws[WS_P01 + 2 * i]);
            pM = fmaxf(pM, ws[WS_P01 + 2 * i + 1]);
        }
        #pragma unroll
        for (int off = 1; off < 64; off <<= 1) {
            pm = fminf(pm, __shfl_xor(pm, off, 64));
            pM = fmaxf(pM, __shfl_xor(pM, off, 64));
        }
        if (tid == 0) {
            float um = fminf(pm, 0.f), uM = fmaxf(pM, 0.f);
            float span = fmaxf(uM - um, 1e-5f);
            float d = span * (1.f / (float)(G - 1));
            float iv = (float)(G - 1) / span;
            ws[WS_RNG + 0] = um; ws[WS_RNG + 1] = d; ws[WS_RNG + 2] = iv;   // net 0
            ws[WS_RNG + 4] = um; ws[WS_RNG + 5] = d; ws[WS_RNG + 6] = iv;   // net 1
            xm_s = pm; xM_s = pM;
        }

        int s0 = 2 * tid, s1 = 2 * tid + 1;
        float w0a = (s0 < DH) ? iW0[(k * DH + s0) * 3] : 0.f;   // h==0: feature 0 only
        float w0b = (s1 < DH) ? iW0[(k * DH + s1) * 3] : 0.f;
        float b0a = (s0 < DH) ? ib0[k * DH + s0] : ((s0 == DH) ? 1.f : 0.f);
        float b0b = (s1 < DH) ? ib0[k * DH + s1] : 0.f;
        w0p_s[tid] = hpk(w0a, w0b);
        b0p_s[tid] = hpk(b0a, b0b);

        int hf_i = tid >> 5, rem = tid & 31;
        int nt2 = rem >> 3, qq = (rem >> 1) & 3, pr = rem & 1;
        int n2e = 32 * nt2 + 8 * qq + 2 * pr + 4 * hf_i;
        float we = (n2e < DH) ? iW3[k * DH + n2e] : 0.f;
        float wo = (n2e + 1 < DH) ? iW3[k * DH + n2e + 1] : 0.f;
        w3p_s[tid] = ((unsigned int)f2bf(wo) << 16) | (unsigned int)f2bf(we);
    }
    for (int i = tid; i < DH * WSTR; i += 256) {
        int r = i / WSTR, c = i - r * WSTR;
        float v1, v2;
        if (c < DH)       { v1 = W1g[r * DH + c]; v2 = W2g[r * DH + c]; }
        else if (c == DH) { v1 = ib1[k * DH + r]; v2 = ib2[k * DH + r]; }
        else              { v1 = 0.f; v2 = 0.f; }
        W1s[r * WSTR + c] = (_Float16)v1;
        W2s[r * WSTR + c] = (_Float16)v2;
    }
    __syncthreads();

    const float b3 = ib3[k];
    const float xm = xm_s, xM = xM_s;

    int wrow[4];
    #pragma unroll
    for (int nt = 0; nt < 4; ++nt) {
        int r = nt * 32 + l31;
        wrow[nt] = ((r > DH - 1) ? (DH - 1) : r) * WSTR + hf * 8;
    }

    union FR { f16x8 v; h2 h[4]; unsigned int u32[4]; };
    const f32x2 zero2 = {0.f, 0.f};

    unsigned int zoff = 0;
    asm volatile("" : "+v"(zoff));   // opaque zero (keeps LDS reads un-cached)

    // rows: r = e*101 + p  (e in {0,1}: xmin/xmax endpoint, p quadrature point)
    int rr[2];
    h2 uu[2];
    #pragma unroll
    for (int j = 0; j < 2; ++j) {
        rr[j] = j * 128 + wv * 32 + l31;
        int r = rr[j];
        float xe = (r < 101) ? xm : xM;
        int p = (r < 101) ? r : (r - 101);
        if (p > 100) p = 0;
        float u = (r < 202) ? xe * ws[WS_XSC + p] : 0.f;
        uu[j] = hpk2(u, u);
    }

    // layer 1: B-frags for both row groups, shared w0/b0 loads
    FR a1[2][7];
    #pragma unroll
    for (int ks = 0; ks < 7; ++ks) {
        int pb = ks * 8 + hf * 4 + zoff;
        uint4 wq = *(const uint4*)&w0p_s[pb];
        uint4 bq = *(const uint4*)&b0p_s[pb];
        unsigned int wqa[4] = {wq.x, wq.y, wq.z, wq.w};
        unsigned int bqa[4] = {bq.x, bq.y, bq.z, bq.w};
        #pragma unroll
        for (int i = 0; i < 4; ++i) {
            union { unsigned int u; h2 h; } cw, cb;
            cw.u = wqa[i]; cb.u = bqa[i];
            h2 z = {(_Float16)0.f, (_Float16)0.f};
            #pragma unroll
            for (int j = 0; j < 2; ++j) {
                h2 r = __builtin_elementwise_fma(uu[j], cw.h, cb.h);
                a1[j][ks].h[i] = __builtin_elementwise_max(r, z);
            }
        }
    }

    // layer 2: dual accumulators share weight loads; pack+exchange -> f3
    FR f3[2][7];
    #pragma unroll
    for (int nt = 0; nt < 4; ++nt) {
        f32x16 acc[2];
        #pragma unroll
        for (int r = 0; r < 16; ++r) { acc[0][r] = 0.f; acc[1][r] = 0.f; }
        #pragma unroll
        for (int ks = 0; ks < 7; ++ks) {
            f16x8 wA = *(const f16x8*)&W1s[wrow[nt] + ks * 16 + zoff];
            acc[0] = __builtin_amdgcn_mfma_f32_32x32x16_f16(wA, a1[0][ks].v, acc[0], 0, 0, 0);
            acc[1] = __builtin_amdgcn_mfma_f32_32x32x16_f16(wA, a1[1][ks].v, acc[1], 0, 0, 0);
        }
        #pragma unroll
        for (int j = 0; j < 2; ++j) {
            if (nt < 3) {
                unsigned int pk[4][2];
                #pragma unroll
                for (int qi = 0; qi < 4; ++qi) {
                    f32x2 lo = {acc[j][4 * qi + 0], acc[j][4 * qi + 1]};
                    f32x2 hi = {acc[j][4 * qi + 2], acc[j][4 * qi + 3]};
                    lo = __builtin_elementwise_max(lo, zero2);
                    hi = __builtin_elementwise_max(hi, zero2);
                    pk[qi][0] = hpk(lo[0], lo[1]);
                    pk[qi][1] = hpk(hi[0], hi[1]);
                }
                #pragma unroll
                for (int kk = 0; kk < 2; ++kk) {
                    unsigned int X0 = hfb ? pk[2 * kk][0] : pk[2 * kk + 1][0];
                    unsigned int X1 = hfb ? pk[2 * kk][1] : pk[2 * kk + 1][1];
                    unsigned int O0 = hfb ? pk[2 * kk + 1][0] : pk[2 * kk][0];
                    unsigned int O1 = hfb ? pk[2 * kk + 1][1] : pk[2 * kk][1];
                    unsigned int Y0 = (unsigned int)__shfl_xor((int)X0, 32, 64);
                    unsigned int Y1 = (unsigned int)__shfl_xor((int)X1, 32, 64);
                    f3[j][nt * 2 + kk].u32[0] = hfb ? Y0 : O0;
                    f3[j][nt * 2 + kk].u32[1] = hfb ? Y1 : O1;
                    f3[j][nt * 2 + kk].u32[2] = hfb ? O0 : Y0;
                    f3[j][nt * 2 + kk].u32[3] = hfb ? O1 : Y1;
                }
            } else {
                f32x2 lo = {acc[j][0], acc[j][1]};
                f32x2 hi = {acc[j][2], acc[j][3]};
                lo = __builtin_elementwise_max(lo, zero2);
                hi = __builtin_elementwise_max(hi, zero2);
                unsigned int p0 = hpk(lo[0], lo[1]);
                unsigned int p1 = hpk(hi[0], hi[1]);
                f3[j][6].u32[0] = hfb ? 0u : p0;
                f3[j][6].u32[1] = hfb ? 0u : p1;
                f3[j][6].u32[2] = hfb ? 0u : 0x00003C00u;   // f16 1.0 (bias slot)
                f3[j][6].u32[3] = 0u;
            }
        }
    }

    // layer 3: dual accumulators; shared W2 + w3 loads; fold w3
    f32x2 oacc2[2] = {{0.f, 0.f}, {0.f, 0.f}};
    #pragma unroll
    for (int nt2 = 0; nt2 < 4; ++nt2) {
        f32x16 acc2[2];
        #pragma unroll
        for (int r = 0; r < 16; ++r) { acc2[0][r] = 0.f; acc2[1][r] = 0.f; }
        #pragma unroll
        for (int ks = 0; ks < 7; ++ks) {
            f16x8 wA = *(const f16x8*)&W2s[wrow[nt2] + ks * 16 + zoff];
            acc2[0] = __builtin_amdgcn_mfma_f32_32x32x16_f16(wA, f3[0][ks].v, acc2[0], 0, 0, 0);
            acc2[1] = __builtin_amdgcn_mfma_f32_32x32x16_f16(wA, f3[1][ks].v, acc2[1], 0, 0, 0);
        }
        uint4 wa = *(const uint4*)&w3p_s[hf * 32 + nt2 * 8 + zoff];
        uint4 wb2 = *(const uint4*)&w3p_s[hf * 32 + nt2 * 8 + 4 + zoff];
        unsigned int w8[8] = {wa.x, wa.y, wa.z, wa.w, wb2.x, wb2.y, wb2.z, wb2.w};
        f32x2 w3v[8];
        #pragma unroll
        for (int q = 0; q < 8; ++q) {
            w3v[q][0] = __uint_as_float(w8[q] << 16);
            w3v[q][1] = __uint_as_float(w8[q] & 0xFFFF0000u);
        }
        #pragma unroll
        for (int j = 0; j < 2; ++j)
            #pragma unroll
            for (int qi = 0; qi < 4; ++qi) {
                f32x2 lo = {acc2[j][4 * qi + 0], acc2[j][4 * qi + 1]};
                f32x2 hi = {acc2[j][4 * qi + 2], acc2[j][4 * qi + 3]};
                lo = __builtin_elementwise_max(lo, zero2);
                hi = __builtin_elementwise_max(hi, zero2);
                oacc2[j] = __builtin_elementwise_fma(lo, w3v[qi * 2], oacc2[j]);
                oacc2[j] = __builtin_elementwise_fma(hi, w3v[qi * 2 + 1], oacc2[j]);
            }
    }

    #pragma unroll
    for (int j = 0; j < 2; ++j) {
        float oacc = oacc2[j][0] + oacc2[j][1];
        float o = oacc + __shfl_xor(oacc, 32, 64) + b3;
        float dz = (o > 0.f) ? (o + 1.f) : expf(o);   // elu(o) + 1
        if (!hfb) g_s[rr[j]] = dz;
    }
    __syncthreads();

    // quadrature at both endpoints -> x2 range -> net-2 table consts
    if (tid < 64) {
        float s0 = 0.f, s1 = 0.f;
        for (int p = tid; p < 101; p += 64) {
            float c = ws[WS_CCW + p];
            s0 = fmaf(c, g_s[p], s0);
            s1 = fmaf(c, g_s[101 + p], s1);
        }
        #pragma unroll
        for (int off = 1; off < 64; off <<= 1) {
            s0 += __shfl_xor(s0, off, 64);
            s1 += __shfl_xor(s1, off, 64);
        }
        if (tid == 0) {
            float z0 = 0.5f * xm * s0;
            float z1 = 0.5f * xM * s1;
            float o0 = ws[WS_OH0 + 0], e1 = ws[WS_EOH1 + 0];
            float a = fmaf(e1, z0, o0);
            float b = fmaf(e1, z1, o0);
            float x2m = fminf(a, b), x2M = fmaxf(a, b);
            float sp = fmaxf(x2M - x2m, 1e-6f);
            x2m -= 0.02f * sp;                 // safety margin: quadrature
            x2M += 0.02f * sp;                 // wiggle + table-lerp error
            float um = fminf(x2m, 0.f), uM = fmaxf(x2M, 0.f);
            float span = fmaxf(uM - um, 1e-5f);
            ws[WS_RNG + 8]  = um;
            ws[WS_RNG + 9]  = span * (1.f / (float)(G - 1));
            ws[WS_RNG + 10] = (float)(G - 1) / span;
        }
    }
}

// build_tab: evaluate g_k(u) = elu(MLP_k(u))+1 on a G-point grid using the
// R3-R11-verified transposed MFMA dataflow. Range consts precomputed by probe.
// One iteration (256 rows) per block -> G/256 blocks per net, all 3 nets at once.
__global__ __launch_bounds__(256)
void build_tab(const float* __restrict__ iW0, const float* __restrict__ ib0,
               const float* __restrict__ iW1, const float* __restrict__ ib1,
               const float* __restrict__ iW2, const float* __restrict__ ib2,
               const float* __restrict__ iW3, const float* __restrict__ ib3,
               float* __restrict__ ws, int kbase)
{
    __shared__ __align__(16) _Float16 W1s[DH * WSTR];
    __shared__ __align__(16) _Float16 W2s[DH * WSTR];
    __shared__ unsigned int w0p_s[64], b0p_s[64], w3p_s[64];
    __shared__ float u0_s, dlt_s;

    const int tid = threadIdx.x;
    const int lane = tid & 63;
    const int wv = tid >> 6;
    const int hf = lane >> 5;
    const bool hfb = (hf != 0);
    const int l31 = lane & 31;
    const int k = kbase + blockIdx.y;
    float* __restrict__ tab = ws + WS_TAB + k * G;

    const float* W1g = iW1 + (size_t)k * DH * DH;
    const float* W2g = iW2 + (size_t)k * DH * DH;

    if (tid < 64) {
        if (tid == 0) {
            u0_s  = ws[WS_RNG + 4 * k];
            dlt_s = ws[WS_RNG + 4 * k + 1];
        }

        int s0 = 2 * tid, s1 = 2 * tid + 1;
        float w0a = (s0 < DH) ? iW0[(k * DH + s0) * 3] : 0.f;   // h==0: feature 0 only
        float w0b = (s1 < DH) ? iW0[(k * DH + s1) * 3] : 0.f;
        float b0a = (s0 < DH) ? ib0[k * DH + s0] : ((s0 == DH) ? 1.f : 0.f);
        float b0b = (s1 < DH) ? ib0[k * DH + s1] : 0.f;
        w0p_s[tid] = hpk(w0a, w0b);
        b0p_s[tid] = hpk(b0a, b0b);

        int hf_i = tid >> 5, rem = tid & 31;
        int nt2 = rem >> 3, qq = (rem >> 1) & 3, pr = rem & 1;
        int n2e = 32 * nt2 + 8 * qq + 2 * pr + 4 * hf_i;
        float we = (n2e < DH) ? iW3[k * DH + n2e] : 0.f;
        float wo = (n2e + 1 < DH) ? iW3[k * DH + n2e + 1] : 0.f;
        w3p_s[tid] = ((unsigned int)f2bf(wo) << 16) | (unsigned int)f2bf(we);
    }
    for (int i = tid; i < DH * WSTR; i += 256) {
        int r = i / WSTR, c = i - r * WSTR;
        float v1, v2;
        if (c < DH)       { v1 = W1g[r * DH + c]; v2 = W2g[r * DH + c]; }
        else if (c == DH) { v1 = ib1[k * DH + r]; v2 = ib2[k * DH + r]; }
        else              { v1 = 0.f; v2 = 0.f; }
        W1s[r * WSTR + c] = (_Float16)v1;
        W2s[r * WSTR + c] = (_Float16)v2;
    }
    __syncthreads();

    const float b3 = ib3[k];
    const float u0 = u0_s, dlt = dlt_s;

    int wrow[4];
    #pragma unroll
    for (int nt = 0; nt < 4; ++nt) {
        int r = nt * 32 + l31;
        wrow[nt] = ((r > DH - 1) ? (DH - 1) : r) * WSTR + hf * 8;
    }

    union FR { f16x8 v; h2 h[4]; unsigned int u32[4]; };
    const f32x2 zero2 = {0.f, 0.f};

    unsigned int zoff = 0;
    asm volatile("" : "+v"(zoff));   // opaque zero (keeps LDS reads un-cached)

    int mr[2];
    h2 uu[2];
    #pragma unroll
    for (int j = 0; j < 2; ++j) {
        mr[j] = blockIdx.x * 256 + j * 128 + wv * 32 + l31;
        float u = fmaf((float)mr[j], dlt, u0);
        uu[j] = hpk2(u, u);
    }

    // layer 1: B-frags for both row groups, shared w0/b0 loads
    FR a1[2][7];
    #pragma unroll
    for (int ks = 0; ks < 7; ++ks) {
        int pb = ks * 8 + hf * 4 + zoff;
        uint4 wq = *(const uint4*)&w0p_s[pb];
        uint4 bq = *(const uint4*)&b0p_s[pb];
        unsigned int wqa[4] = {wq.x, wq.y, wq.z, wq.w};
        unsigned int bqa[4] = {bq.x, bq.y, bq.z, bq.w};
        #pragma unroll
        for (int i = 0; i < 4; ++i) {
            union { unsigned int u; h2 h; } cw, cb;
            cw.u = wqa[i]; cb.u = bqa[i];
            h2 z = {(_Float16)0.f, (_Float16)0.f};
            #pragma unroll
            for (int j = 0; j < 2; ++j) {
                h2 r = __builtin_elementwise_fma(uu[j], cw.h, cb.h);
                a1[j][ks].h[i] = __builtin_elementwise_max(r, z);
            }
        }
    }

    // layer 2: dual accumulators share weight loads; pack+exchange -> f3
    FR f3[2][7];
    #pragma unroll
    for (int nt = 0; nt < 4; ++nt) {
        f32x16 acc[2];
        #pragma unroll
        for (int r = 0; r < 16; ++r) { acc[0][r] = 0.f; acc[1][r] = 0.f; }
        #pragma unroll
        for (int ks = 0; ks < 7; ++ks) {
            f16x8 wA = *(const f16x8*)&W1s[wrow[nt] + ks * 16 + zoff];
            acc[0] = __builtin_amdgcn_mfma_f32_32x32x16_f16(wA, a1[0][ks].v, acc[0], 0, 0, 0);
            acc[1] = __builtin_amdgcn_mfma_f32_32x32x16_f16(wA, a1[1][ks].v, acc[1], 0, 0, 0);
        }
        #pragma unroll
        for (int j = 0; j < 2; ++j) {
            if (nt < 3) {
                unsigned int pk[4][2];
                #pragma unroll
                for (int qi = 0; qi < 4; ++qi) {
                    f32x2 lo = {acc[j][4 * qi + 0], acc[j][4 * qi + 1]};
                    f32x2 hi = {acc[j][4 * qi + 2], acc[j][4 * qi + 3]};
                    lo = __builtin_elementwise_max(lo, zero2);
                    hi = __builtin_elementwise_max(hi, zero2);
                    pk[qi][0] = hpk(lo[0], lo[1]);
                    pk[qi][1] = hpk(hi[0], hi[1]);
                }
                #pragma unroll
                for (int kk = 0; kk < 2; ++kk) {
                    unsigned int X0 = hfb ? pk[2 * kk][0] : pk[2 * kk + 1][0];
                    unsigned int X1 = hfb ? pk[2 * kk][1] : pk[2 * kk + 1][1];
                    unsigned int O0 = hfb ? pk[2 * kk + 1][0] : pk[2 * kk][0];
                    unsigned int O1 = hfb ? pk[2 * kk + 1][1] : pk[2 * kk][1];
                    unsigned int Y0 = (unsigned int)__shfl_xor((int)X0, 32, 64);
                    unsigned int Y1 = (unsigned int)__shfl_xor((int)X1, 32, 64);
                    f3[j][nt * 2 + kk].u32[0] = hfb ? Y0 : O0;
                    f3[j][nt * 2 + kk].u32[1] = hfb ? Y1 : O1;
                    f3[j][nt * 2 + kk].u32[2] = hfb ? O0 : Y0;
                    f3[j][nt * 2 + kk].u32[3] = hfb ? O1 : Y1;
                }
            } else {
                f32x2 lo = {acc[j][0], acc[j][1]};
                f32x2 hi = {acc[j][2], acc[j][3]};
                lo = __builtin_elementwise_max(lo, zero2);
                hi = __builtin_elementwise_max(hi, zero2);
                unsigned int p0 = hpk(lo[0], lo[1]);
                unsigned int p1 = hpk(hi[0], hi[1]);
                f3[j][6].u32[0] = hfb ? 0u : p0;
                f3[j][6].u32[1] = hfb ? 0u : p1;
                f3[j][6].u32[2] = hfb ? 0u : 0x00003C00u;   // f16 1.0 (bias slot)
                f3[j][6].u32[3] = 0u;
            }
        }
    }

    // layer 3: dual accumulators; shared W2 + w3 loads; fold w3
    f32x2 oacc2[2] = {{0.f, 0.f}, {0.f, 0.f}};
    #pragma unroll
    for (int nt2 = 0; nt2 < 4; ++nt2) {
        f32x16 acc2[2];
        #pragma unroll
        for (int r = 0; r < 16; ++r) { acc2[0][r] = 0.f; acc2[1][r] = 0.f; }
        #pragma unroll
        for (int ks = 0; ks < 7; ++ks) {
            f16x8 wA = *(const f16x8*)&W2s[wrow[nt2] + ks * 16 + zoff];
            acc2[0] = __builtin_amdgcn_mfma_f32_32x32x16_f16(wA, f3[0][ks].v, acc2[0], 0, 0, 0);
            acc2[1] = __builtin_amdgcn_mfma_f32_32x32x16_f16(wA, f3[1][ks].v, acc2[1], 0, 0, 0);
        }
        uint4 wa = *(const uint4*)&w3p_s[hf * 32 + nt2 * 8 + zoff];
        uint4 wb2 = *(const uint4*)&w3p_s[hf * 32 + nt2 * 8 + 4 + zoff];
        unsigned int w8[8] = {wa.x, wa.y, wa.z, wa.w, wb2.x, wb2.y, wb2.z, wb2.w};
        f32x2 w3v[8];
        #pragma unroll
        for (int q = 0; q < 8; ++q) {
            w3v[q][0] = __uint_as_float(w8[q] << 16);
            w3v[q][1] = __uint_as_float(w8[q] & 0xFFFF0000u);
        }
        #pragma unroll
        for (int j = 0; j < 2; ++j)
            #pragma unroll
            for (int qi = 0; qi < 4; ++qi) {
                f32x2 lo = {acc2[j][4 * qi + 0], acc2[j][4 * qi + 1]};
                f32x2 hi = {acc2[j][4 * qi + 2], acc2[j][4 * qi + 3]};
                lo = __builtin_elementwise_max(lo, zero2);
                hi = __builtin_elementwise_max(hi, zero2);
                oacc2[j] = __builtin_elementwise_fma(lo, w3v[qi * 2], oacc2[j]);
                oacc2[j] = __builtin_elementwise_fma(hi, w3v[qi * 2 + 1], oacc2[j]);
            }
    }

    #pragma unroll
    for (int j = 0; j < 2; ++j) {
        float oacc = oacc2[j][0] + oacc2[j][1];
        float o = oacc + __shfl_xor(oacc, 32, 64) + b3;
        float dz = (o > 0.f) ? (o + 1.f) : expf(o);   // elu(o) + 1
        if (!hfb) tab[mr[j]] = dz;
    }
}

// quadrature of one net's table: z = sum_p ccw[p] * lerp(tab, x*xsc[p]),
// 4 threads/sample (point-strided), butterfly reduce over the 4-lane group.
__device__ __forceinline__ float quadz(const float* __restrict__ tab_s,
                                       const float* __restrict__ xsc_s,
                                       const float* __restrict__ ccw_s,
                                       float x, float u0, float invd, int psub)
{
    float z = 0.f;
    for (int p = psub; p < 101; p += 4) {
        float u = x * xsc_s[p];
        float tt = fminf(fmaxf((u - u0) * invd, 0.f), (float)(G - 1) - 0.001f);
        int i = (int)tt;
        float f = tt - (float)i;
        float g0 = tab_s[i];
        float g1 = tab_s[i + 1];
        z = fmaf(ccw_s[p], fmaf(f, g1 - g0, g0), z);
    }
    z += __shfl_xor(z, 1, 64);
    z += __shfl_xor(z, 2, 64);
    return z;
}

// eval_fused: 64 samples/block, 4 threads/sample.
// blockIdx.y==1: y1 = mono(1, x).  blockIdx.y==0: x2 = mono(0, x) kept in
// registers, then y2 = mono(2, x2) — both tables resident in LDS.
__global__ __launch_bounds__(256)
void eval_fused(const float* __restrict__ logits, float* __restrict__ out,
                const float* __restrict__ ws, int n)
{
    __shared__ float tabA_s[G];
    __shared__ float tabB_s[G];
    __shared__ float xsc_s[104], ccw_s[104];
    __shared__ float cst_s[8];   // u0A,invA,o0A,e1A, u0B,invB,o0B,e1B

    const int tid = threadIdx.x;
    const bool chain = (blockIdx.y == 0);

    if (chain) {
        const float* tg0 = ws + WS_TAB + 0 * G;
        const float* tg2 = ws + WS_TAB + 2 * G;
        for (int i = tid; i < G; i += 256) { tabA_s[i] = tg0[i]; tabB_s[i] = tg2[i]; }
    } else {
        const float* tg1 = ws + WS_TAB + 1 * G;
        for (int i = tid; i < G; i += 256) tabA_s[i] = tg1[i];
    }
    if (tid < 104) {
        xsc_s[tid] = (tid < 101) ? ws[WS_XSC + tid] : 0.f;
        ccw_s[tid] = (tid < 101) ? ws[WS_CCW + tid] : 0.f;
    }
    if (tid < 8) {
        int kk = (tid < 4) ? (chain ? 0 : 1) : (chain ? 2 : 1);
        int which = tid & 3;
        float v;
        if (which == 0)      v = ws[WS_RNG + 4 * kk];
        else if (which == 1) v = ws[WS_RNG + 4 * kk + 2];
        else if (which == 2) v = ws[WS_OH0 + kk];
        else                 v = ws[WS_EOH1 + kk];
        cst_s[tid] = v;
    }
    __syncthreads();

    const int nn = blockIdx.x * SPB_E + (tid >> 2);
    const int psub = tid & 3;
    const float x = (nn < n) ? logits[nn] : 0.f;

    float z = quadz(tabA_s, xsc_s, ccw_s, x, cst_s[0], cst_s[1], psub);
    float yA = fmaf(cst_s[3], 0.5f * x * z, cst_s[2]);

    if (chain) {
        float x2 = yA;
        float z2 = quadz(tabB_s, xsc_s, ccw_s, x2, cst_s[4], cst_s[5], psub);
        float y2 = fmaf(cst_s[7], 0.5f * x2 * z2, cst_s[6]);
        if (nn < n && psub == 0) out[n + nn] = y2;
    } else {
        if (nn < n && psub == 0) out[nn] = yA;
    }
}

extern "C" void kernel_launch(void* const* d_in, const int* in_sizes, int n_in,
                              void* d_out, int out_size, void* d_ws, size_t ws_size,
                              hipStream_t stream)
{
    const float* logits = (const float*)d_in[0];
    const float* iW0 = (const float*)d_in[2];
    const float* ib0 = (const float*)d_in[3];
    const float* iW1 = (const float*)d_in[4];
    const float* ib1 = (const float*)d_in[5];
    const float* iW2 = (const float*)d_in[6];
    const float* ib2 = (const float*)d_in[7];
    const float* iW3 = (const float*)d_in[8];
    const float* ib3 = (const float*)d_in[9];
    const float* hb0 = (const float*)d_in[11];
    const float* hW1 = (const float*)d_in[12];
    const float* hb1 = (const float*)d_in[13];
    const float* hW2 = (const float*)d_in[14];
    const float* hb2 = (const float*)d_in[15];
    const float* hW3 = (const float*)d_in[16];
    const float* hb3 = (const float*)d_in[17];
    float* out = (float*)d_out;
    float* ws = (float*)d_ws;
    int n = in_sizes[0];
    int nbE = (n + SPB_E - 1) / SPB_E;     // 256 blocks at N=16384

    // 1) consts + logits passthrough + logits min/max partials (64 pairs)
    hipLaunchKernelGGL(prep_kernel, dim3(64), dim3(256), 0, stream,
                       logits, hb0, hW1, hb1, hW2, hb2, hW3, hb3, ws, out + 2 * n, n);
    // 2) range consts for all 3 nets (net-2 via 2-endpoint monotonicity probe)
    hipLaunchKernelGGL(probe_kernel, dim3(1), dim3(256), 0, stream,
                       iW0, ib0, iW1, ib1, iW2, ib2, iW3, ib3, ws, 64);
    // 3) all three tables concurrently
    hipLaunchKernelGGL(build_tab, dim3(G / 256, 3), dim3(256), 0, stream,
                       iW0, ib0, iW1, ib1, iW2, ib2, iW3, ib3, ws, 0);
    // 4) fused eval: y1 (slice 1) and x2->y2 chain in registers (slice 0)
    hipLaunchKernelGGL(eval_fused, dim3(nbE, 2), dim3(256), 0, stream,
                       logits, out, ws, n);
}